// Round 12
// baseline (2224.974 us; speedup 1.0000x reference)
//
#include <hip/hip_runtime.h>

#define BB 16
#define TZ_ 2048
#define TT_ 512
#define D_ 256
#define DFF_ 1024
#define L_ 6
#define HEADS_ 4
#define DH_ 64
#define CH_ 256
#define HID_ 256
#define KCV 5
#define FLOWS_ 4
#define G_ 256
#define NEGF (-1000000000.0f)
#define LOG2PI 1.8378770664093453f

typedef unsigned short u16;
typedef __attribute__((ext_vector_type(8))) short short8v;
typedef __attribute__((ext_vector_type(4))) float f32x4;
typedef __attribute__((ext_vector_type(4))) unsigned u4v;

__device__ __forceinline__ float wsum(float v){
#pragma unroll
  for (int o = 32; o; o >>= 1) v += __shfl_xor(v, o);
  return v;
}
__device__ __forceinline__ u16 f2bf(float x){
  unsigned u = __float_as_uint(x);
  return (u16)((u + 0x7FFFu + ((u >> 16) & 1u)) >> 16);
}
__device__ __forceinline__ float bf2f(u16 h){
  return __uint_as_float(((unsigned)h) << 16);
}
__device__ __forceinline__ unsigned pk2f(float a, float b){
  return __builtin_amdgcn_perm(__float_as_uint(b), __float_as_uint(a), 0x07060302u);
}
__device__ __forceinline__ float trnc(float f){
  return __uint_as_float(__float_as_uint(f) & 0xFFFF0000u);
}
__device__ __forceinline__ void cvt8t(float4 x, float4 y, uint4 &hi, uint4 &lo){
  hi.x = pk2f(x.x, x.y); hi.y = pk2f(x.z, x.w);
  hi.z = pk2f(y.x, y.y); hi.w = pk2f(y.z, y.w);
  float r0 = x.x - trnc(x.x), r1 = x.y - trnc(x.y), r2 = x.z - trnc(x.z), r3 = x.w - trnc(x.w);
  float r4 = y.x - trnc(y.x), r5 = y.y - trnc(y.y), r6 = y.z - trnc(y.z), r7 = y.w - trnc(y.w);
  lo.x = pk2f(r0, r1); lo.y = pk2f(r2, r3); lo.z = pk2f(r4, r5); lo.w = pk2f(r6, r7);
}
__device__ __forceinline__ unsigned rneh(float f){
  unsigned v = __float_as_uint(f);
  return (v + 0x7FFFu + ((v >> 16) & 1u)) & 0xFFFF0000u;
}
__device__ __forceinline__ void cvt8r(float4 x, float4 y, uint4 &hi, uint4 &lo){
  unsigned h0=rneh(x.x), h1=rneh(x.y), h2=rneh(x.z), h3=rneh(x.w);
  unsigned h4=rneh(y.x), h5=rneh(y.y), h6=rneh(y.z), h7=rneh(y.w);
  hi.x = h1 | (h0>>16); hi.y = h3 | (h2>>16); hi.z = h5 | (h4>>16); hi.w = h7 | (h6>>16);
  float r0 = x.x - __uint_as_float(h0), r1 = x.y - __uint_as_float(h1);
  float r2 = x.z - __uint_as_float(h2), r3 = x.w - __uint_as_float(h3);
  float r4 = y.x - __uint_as_float(h4), r5 = y.y - __uint_as_float(h5);
  float r6 = y.z - __uint_as_float(h6), r7 = y.w - __uint_as_float(h7);
  lo.x = pk2f(r0, r1); lo.y = pk2f(r2, r3); lo.z = pk2f(r4, r5); lo.w = pk2f(r6, r7);
}

// ---------------- positional encoding ----------------
__global__ void k_pe(float* __restrict__ pe){
  int t = blockIdx.x, d = threadIdx.x;
  double e = (double)(2*(d>>1)) / (double)D_;
  double ang = (double)t * pow(10000.0, -e);
  pe[t*D_ + d] = (float)(((d&1)==0) ? sin(ang) : cos(ang));
}
// ---------------- embedding ----------------
__global__ void k_embed(const int* __restrict__ text, const float* __restrict__ emb,
                        const float* __restrict__ pe, float* __restrict__ h){
  int row = blockIdx.x, d = threadIdx.x;
  h[(size_t)row*D_ + d] = emb[(size_t)text[row]*D_ + d]*16.0f + pe[(row%TT_)*D_ + d];
}

// ---------------- weight transposes (74 slots of 256x256) ----------------
__global__ __launch_bounds__(256) void k_wt(
  const float* __restrict__ wq, const float* __restrict__ wk,
  const float* __restrict__ wv, const float* __restrict__ wo,
  const float* __restrict__ mu_w, const float* __restrict__ lv_w,
  const float* __restrict__ w1, const float* __restrict__ w2,
  float* __restrict__ QKVT, float* __restrict__ OT, float* __restrict__ MULVT,
  float* __restrict__ W1T, float* __restrict__ W2T)
{
  __shared__ float td[64][65];
  const int s = blockIdx.y, tile = blockIdx.x, t = threadIdx.x;
  const float* inb; float* outb; int istride, ostride;
  if (s < 24){
    int l = s>>2, wsel = s&3;
    const float* w = (wsel==0?wq:wsel==1?wk:wsel==2?wv:wo);
    inb = w + (size_t)l*65536; istride = 256;
    if (wsel < 3) outb = QKVT + (size_t)l*196608 + wsel*65536;
    else          outb = OT   + (size_t)l*65536;
    ostride = 256;
  } else if (s < 26){
    inb = (s==24 ? mu_w : lv_w); istride = 256;
    outb = MULVT + (size_t)(s-24)*65536; ostride = 256;
  } else if (s < 50){
    int idx = s-26, l = idx>>2, b2 = idx&3;
    inb = w1 + (size_t)l*262144 + b2*256; istride = 1024;
    outb = W1T + (size_t)l*262144 + (size_t)b2*65536; ostride = 256;
  } else {
    int idx = s-50, l = idx>>2, b2 = idx&3;
    inb = w2 + (size_t)l*262144 + (size_t)b2*65536; istride = 256;
    outb = W2T + (size_t)l*262144 + b2*256; ostride = 1024;
  }
  const int kt = (tile>>2)*64, nt = (tile&3)*64;
  const int r = t>>2, cq = (t&3)*16;
#pragma unroll
  for (int c=0;c<16;c+=4){
    float4 v = *(const float4*)(inb + (size_t)(kt + r)*istride + nt + cq + c);
    td[r][cq+c+0]=v.x; td[r][cq+c+1]=v.y; td[r][cq+c+2]=v.z; td[r][cq+c+3]=v.w;
  }
  __syncthreads();
#pragma unroll
  for (int c=0;c<16;c+=4){
    float4 v = make_float4(td[cq+c+0][r], td[cq+c+1][r], td[cq+c+2][r], td[cq+c+3][r]);
    *(float4*)(outb + (size_t)(nt + r)*ostride + kt + cq + c) = v;
  }
}

// ---------------- V transpose per layer ----------------
__global__ __launch_bounds__(256) void k_vt(const float* __restrict__ QKV, float* __restrict__ VT){
  __shared__ float td[64][65];
  const int b = blockIdx.z, dt = blockIdx.x, jt = blockIdx.y, t = threadIdx.x;
  const float* inb = QKV + (size_t)b*512*768 + 512;
  float* outb = VT + (size_t)b*131072;
  const int r = t>>2, cq = (t&3)*16;
#pragma unroll
  for (int c=0;c<16;c+=4){
    float4 v = *(const float4*)(inb + (size_t)(jt*64 + r)*768 + dt*64 + cq + c);
    td[r][cq+c+0]=v.x; td[r][cq+c+1]=v.y; td[r][cq+c+2]=v.z; td[r][cq+c+3]=v.w;
  }
  __syncthreads();
#pragma unroll
  for (int c=0;c<16;c+=4){
    float4 v = make_float4(td[cq+c+0][r], td[cq+c+1][r], td[cq+c+2][r], td[cq+c+3][r]);
    *(float4*)(outb + (size_t)(dt*64 + r)*512 + jt*64 + cq + c) = v;
  }
}

// ---------------- bias concat ----------------
__global__ void k_bcat(const float* __restrict__ bq, const float* __restrict__ bk,
                       const float* __restrict__ bv, const float* __restrict__ mu_b,
                       const float* __restrict__ lv_b,
                       float* __restrict__ BQKV, float* __restrict__ MULVB){
  int i = blockIdx.x*256 + threadIdx.x;
  if (i < 4608){
    int l = i/768, c = i%768;
    float v = c<256 ? bq[l*256+c] : (c<512 ? bk[l*256+c-256] : bv[l*256+c-512]);
    BQKV[i] = v;
  } else if (i < 5120){
    int c = i-4608;
    MULVB[c] = c<256 ? mu_b[c] : lv_b[c-256];
  }
}

// =========== universal split-bf16 MFMA GEMM (software-pipelined K loop) ===========
template<int WN, int EPI, int AM, int BMD>
__global__ __launch_bounds__(256,2) void k_mg(
  const void* __restrict__ Ap, const void* __restrict__ ApL, int lda, int azhi, int azlo,
  const void* __restrict__ Bp, const void* __restrict__ BpL, int ldb, int bzhi, int bzlo,
  const float* __restrict__ bias, const int* __restrict__ text,
  const float* __restrict__ nc1v, const float* __restrict__ nc4v,
  float* __restrict__ C, int ldc, int czhi, int czlo, int K)
{
  constexpr int BN = WN*32;
  __shared__ u16 AH[4096], AL[4096];
  __shared__ u16 BH[BN*32], BL[BN*32];
  char* AHB=(char*)AH; char* ALB=(char*)AL; char* BHB=(char*)BH; char* BLB=(char*)BL;
  const int t = threadIdx.x, z = blockIdx.z;
  const int m0 = blockIdx.y*128, n0 = blockIdx.x*BN;
  const size_t aoff = (size_t)(z>>2)*azhi + (size_t)(z&3)*azlo;
  const size_t boff = (size_t)(z>>2)*bzhi + (size_t)(z&3)*bzlo;
  const size_t coff = (size_t)(z>>2)*czhi + (size_t)(z&3)*czlo;
  const int w = t>>6, l = t&63;
  const int wr = (w>>1)*64, wc = (w&1)*(WN*16);
  const int lr = l&15, lg = l>>4;
  const int srow = t>>1, sseg = t&1;
  const int q  = (srow>>1)&3;
  const int wo0 = srow*64 + ((((sseg<<1)|0)^q)<<4);
  const int wo1 = srow*64 + ((((sseg<<1)|1)^q)<<4);
  const bool bact = (WN==4) || (t < 128);
  const int qa = ((wr+lr)>>1)&3, qb2 = ((wc+lr)>>1)&3;
  const int raBase = (wr+lr)*64 + ((lg^qa)<<4);
  const int rbBase = (wc+lr)*64 + ((lg^qb2)<<4);

  const float* Af = nullptr; const u16* AfH = nullptr; const u16* AfL = nullptr;
  if constexpr (AM==0 || AM==2){ Af = (const float*)Ap + aoff; }
  else { AfH = (const u16*)Ap + aoff; AfL = (const u16*)ApL + aoff; }
  const float* Bf = nullptr; const u16* BfH = nullptr; const u16* BfL = nullptr;
  if constexpr (BMD==0){ Bf = (const float*)Bp + boff; }
  else { BfH = (const u16*)Bp + boff; BfL = (const u16*)BpL + boff; }

  float4 sa0, sa1, sa2, sa3;
  uint4  pah0, pah1, pal0, pal1;
  float4 sb0, sb1, sb2, sb3;
  uint4  pbh0, pbh1, pbl0, pbl1;

  auto LOADA = [&](int kk){
    if constexpr (AM==0){
      const float* p = Af + (size_t)(m0+srow)*lda + kk + sseg*16;
      sa0=*(const float4*)p; sa1=*(const float4*)(p+4);
      sa2=*(const float4*)(p+8); sa3=*(const float4*)(p+12);
    } else if constexpr (AM==1){
      const u16* ph = AfH + (size_t)(m0+srow)*lda + kk + sseg*16;
      const u16* pl = AfL + (size_t)(m0+srow)*lda + kk + sseg*16;
      pah0 = *(const uint4*)ph; pah1 = *(const uint4*)(ph+8);
      pal0 = *(const uint4*)pl; pal1 = *(const uint4*)(pl+8);
    } else {
      int kg = kk + sseg*16;
      const float* p = Af + (size_t)(m0+srow)*lda + (kg < 256 ? kg : kg - 256);
      sa0=*(const float4*)p; sa1=*(const float4*)(p+4);
      sa2=*(const float4*)(p+8); sa3=*(const float4*)(p+12);
    }
  };
  auto LOADB = [&](int kk){
    if constexpr (BMD==0){
      const float* p = Bf + (size_t)(n0+srow)*ldb + kk + sseg*16;
      sb0=*(const float4*)p; sb1=*(const float4*)(p+4);
      sb2=*(const float4*)(p+8); sb3=*(const float4*)(p+12);
    } else {
      const u16* ph = BfH + (size_t)(n0+srow)*ldb + kk + sseg*16;
      const u16* pl = BfL + (size_t)(n0+srow)*ldb + kk + sseg*16;
      pbh0 = *(const uint4*)ph; pbh1 = *(const uint4*)(ph+8);
      pbl0 = *(const uint4*)pl; pbl1 = *(const uint4*)(pl+8);
    }
  };
  auto WRITEA = [&](int kk){
    uint4 ahi0, ahi1, alo0, alo1;
    if constexpr (AM==0){
      cvt8t(sa0,sa1,ahi0,alo0); cvt8t(sa2,sa3,ahi1,alo1);
    } else if constexpr (AM==1){
      ahi0=pah0; ahi1=pah1; alo0=pal0; alo1=pal1;
    } else {
      float4 a0=sa0, a1=sa1, a2=sa2, a3=sa3;
      int kg = kk + sseg*16;
      if (kg >= 256){
        a0.x=-0.5f*a0.x*a0.x; a0.y=-0.5f*a0.y*a0.y; a0.z=-0.5f*a0.z*a0.z; a0.w=-0.5f*a0.w*a0.w;
        a1.x=-0.5f*a1.x*a1.x; a1.y=-0.5f*a1.y*a1.y; a1.z=-0.5f*a1.z*a1.z; a1.w=-0.5f*a1.w*a1.w;
        a2.x=-0.5f*a2.x*a2.x; a2.y=-0.5f*a2.y*a2.y; a2.z=-0.5f*a2.z*a2.z; a2.w=-0.5f*a2.w*a2.w;
        a3.x=-0.5f*a3.x*a3.x; a3.y=-0.5f*a3.y*a3.y; a3.z=-0.5f*a3.z*a3.z; a3.w=-0.5f*a3.w*a3.w;
      }
      cvt8r(a0,a1,ahi0,alo0); cvt8r(a2,a3,ahi1,alo1);
    }
    *(uint4*)(AHB + wo0) = ahi0;  *(uint4*)(AHB + wo1) = ahi1;
    *(uint4*)(ALB + wo0) = alo0;  *(uint4*)(ALB + wo1) = alo1;
  };
  auto WRITEB = [&](){
    uint4 bhi0, bhi1, blo0, blo1;
    if constexpr (BMD==0){
      cvt8t(sb0,sb1,bhi0,blo0); cvt8t(sb2,sb3,bhi1,blo1);
    } else {
      bhi0=pbh0; bhi1=pbh1; blo0=pbl0; blo1=pbl1;
    }
    *(uint4*)(BHB + wo0) = bhi0;  *(uint4*)(BHB + wo1) = bhi1;
    *(uint4*)(BLB + wo0) = blo0;  *(uint4*)(BLB + wo1) = blo1;
  };

  f32x4 acc[4][WN];
#pragma unroll
  for (int i=0;i<4;i++)
#pragma unroll
    for (int j=0;j<WN;j++) acc[i][j] = (f32x4){0.f,0.f,0.f,0.f};

  LOADA(0);
  if (bact) LOADB(0);
  for (int k0 = 0; k0 < K; k0 += 32){
    __syncthreads();
    WRITEA(k0);
    if (bact) WRITEB();
    if (k0 + 32 < K){ LOADA(k0+32); if (bact) LOADB(k0+32); }
    __syncthreads();
    short8v fah[4], fal[4], fbh[WN], fbl[WN];
#pragma unroll
    for (int i=0;i<4;i++){
      fah[i] = *(short8v*)(AHB + raBase + i*1024);
      fal[i] = *(short8v*)(ALB + raBase + i*1024);
    }
#pragma unroll
    for (int j=0;j<WN;j++){
      fbh[j] = *(short8v*)(BHB + rbBase + j*1024);
      fbl[j] = *(short8v*)(BLB + rbBase + j*1024);
    }
#pragma unroll
    for (int i=0;i<4;i++)
#pragma unroll
      for (int j=0;j<WN;j++){
        acc[i][j] = __builtin_amdgcn_mfma_f32_16x16x32_bf16(fah[i], fbh[j], acc[i][j], 0,0,0);
        acc[i][j] = __builtin_amdgcn_mfma_f32_16x16x32_bf16(fal[i], fbh[j], acc[i][j], 0,0,0);
        acc[i][j] = __builtin_amdgcn_mfma_f32_16x16x32_bf16(fah[i], fbl[j], acc[i][j], 0,0,0);
      }
  }

#pragma unroll
  for (int i=0;i<4;i++){
    int mm0 = m0 + wr + i*16 + (lg<<2);
#pragma unroll
    for (int j=0;j<WN;j++){
      int nn = n0 + wc + j*16 + lr;
      float bs = 0.f; float ncb = 0.f; bool msk = true;
      if (EPI==0 || EPI==1) bs = bias ? bias[nn] : 0.f;
      if (EPI==2) msk = (text[(z>>2)*TT_ + nn] != 0);
      if (EPI==3){ ncb = nc1v[z*TT_+nn] + nc4v[z*TT_+nn]; msk = (text[z*TT_+nn] != 0); }
      f32x4 v = acc[i][j];
#pragma unroll
      for (int r=0;r<4;r++){
        int m = mm0 + r;
        float x;
        if (EPI==0)      x = v[r] + bs;
        else if (EPI==1) x = fmaxf(v[r] + bs, 0.f);
        else if (EPI==2) x = v[r]*0.125f + (msk ? 0.f : NEGF);
        else             x = msk ? (v[r] + ncb) : NEGF;
        C[coff + (size_t)m*ldc + nn] = x;
      }
    }
  }
}

// ---------------- row softmax over 512 (4 rows per block) ----------------
__global__ __launch_bounds__(256) void k_softmax(float* __restrict__ S){
  size_t row = (size_t)blockIdx.x*4 + (threadIdx.x >> 6);
  float* p = S + row*TT_;
  int ln = threadIdx.x & 63;
  float4 a = *(float4*)(p + ln*8);
  float4 b = *(float4*)(p + ln*8 + 4);
  float x[8] = {a.x,a.y,a.z,a.w,b.x,b.y,b.z,b.w};
  float m = x[0];
#pragma unroll
  for (int i=1;i<8;i++) m = fmaxf(m, x[i]);
#pragma unroll
  for (int o2=32;o2;o2>>=1) m = fmaxf(m, __shfl_xor(m, o2));
  float s = 0.f;
#pragma unroll
  for (int i=0;i<8;i++){ x[i] = expf(x[i]-m); s += x[i]; }
  s = wsum(s);
  float inv = 1.0f/s;
  *(float4*)(p + ln*8)     = make_float4(x[0]*inv, x[1]*inv, x[2]*inv, x[3]*inv);
  *(float4*)(p + ln*8 + 4) = make_float4(x[4]*inv, x[5]*inv, x[6]*inv, x[7]*inv);
}

// ---------------- residual + LayerNorm ----------------
__global__ __launch_bounds__(256) void k_lnres(const float* __restrict__ y,
  const float* __restrict__ g, const float* __restrict__ bb, float* __restrict__ h){
  size_t row = blockIdx.x; int d = threadIdx.x;
  float v = h[row*D_ + d] + y[row*D_ + d];
  float s = wsum(v), s2 = wsum(v*v);
  __shared__ float r1[4], r2[4];
  int w = d >> 6;
  if ((d & 63) == 0){ r1[w] = s; r2[w] = s2; }
  __syncthreads();
  s  = r1[0]+r1[1]+r1[2]+r1[3];
  s2 = r2[0]+r2[1]+r2[2]+r2[3];
  float mean = s * (1.0f/D_);
  float var  = s2 * (1.0f/D_) - mean*mean;
  float inv  = rsqrtf(var + 1e-6f);
  h[row*D_ + d] = g[d]*(v - mean)*inv + bb[d];
}

// ---------------- prep: nc1/nc4 + B2 split planes [msp | spr] ----------------
__global__ __launch_bounds__(256) void k_prep(const float* __restrict__ mulv,
  u16* __restrict__ b2h, u16* __restrict__ b2l,
  float* __restrict__ nc1, float* __restrict__ nc4){
  size_t row = blockIdx.x; int d = threadIdx.x;
  float m = mulv[row*512 + d];
  float lv = mulv[row*512 + 256 + d];
  float sp = expf(-lv);
  float ms = m*sp;
  float s1 = wsum(lv), s2 = wsum(m*ms);
  __shared__ float r1[4], r2[4];
  int w = d >> 6;
  if ((d&63)==0){ r1[w]=s1; r2[w]=s2; }
  __syncthreads();
  if (d == 0){
    nc1[row] = -0.5f*((float)D_*LOG2PI + (r1[0]+r1[1]+r1[2]+r1[3]));
    nc4[row] = -0.5f*(r2[0]+r2[1]+r2[2]+r2[3]);
  }
  unsigned hm = rneh(ms);
  b2h[row*512 + d] = (u16)(hm>>16);
  b2l[row*512 + d] = f2bf(ms - __uint_as_float(hm));
  unsigned hs = rneh(sp);
  b2h[row*512 + 256 + d] = (u16)(hs>>16);
  b2l[row*512 + 256 + d] = f2bf(sp - __uint_as_float(hs));
}

// ---------------- fused per-flow prep: wprep + x0prep + condproj ----------------
__global__ __launch_bounds__(256) void k_fprep(
  const float* __restrict__ win, const float* __restrict__ wconv, const float* __restrict__ wout,
  u16* __restrict__ WITH, u16* __restrict__ WITL,
  u16* __restrict__ WCTH, u16* __restrict__ WCTL,
  u16* __restrict__ WOTH, u16* __restrict__ WOTL,
  const float* __restrict__ zsrc, u16* __restrict__ xh, u16* __restrict__ xl,
  const float* __restrict__ cond, const float* __restrict__ fcw, float* __restrict__ condp)
{
  const int bid = blockIdx.x, t = threadIdx.x;
  if (bid < 1536){
    int i = bid*256 + t;
    float wv2; u16 *dh, *dl; int idx;
    if (i < 32768){
      int n = i >> 7, k = i & 127;
      wv2 = win[k*256 + n]; dh = WITH; dl = WITL; idx = i;
    } else if (i < 360448){
      int jj = i - 32768;
      int o = jj / 1280, r = jj - o*1280;
      wv2 = wconv[(size_t)r*256 + o]; dh = WCTH; dl = WCTL; idx = jj;
    } else {
      int jj = i - 360448;
      int o = jj >> 8, k = jj & 255;
      wv2 = wout[k*128 + o]; dh = WOTH; dl = WOTL; idx = jj;
    }
    u16 hh = f2bf(wv2);
    dh[idx] = hh;
    dl[idx] = f2bf(wv2 - bf2f(hh));
  } else if (bid < 3584){
    size_t i = ((size_t)(bid-1536)*256 + t) << 3;
    size_t m2 = i >> 7; int k = (int)(i & 127);
    const float* src = zsrc + m2*256 + k;
    float4 a = *(const float4*)src; float4 b2 = *(const float4*)(src+4);
    float vv[8] = {a.x,a.y,a.z,a.w,b2.x,b2.y,b2.z,b2.w};
    short8v oh, ol;
#pragma unroll
    for (int r=0;r<8;r++){
      u16 hh = f2bf(vv[r]);
      oh[r] = (short)hh;
      ol[r] = (short)f2bf(vv[r] - bf2f(hh));
    }
    *(short8v*)(xh + i) = oh;
    *(short8v*)(xl + i) = ol;
  } else {
    int b = bid - 3584, n = t;
    float s = 0.f;
    for (int k2=0;k2<G_;k2++) s = fmaf(cond[b*G_ + k2], fcw[k2*HID_ + n], s);
    condp[b*HID_ + n] = s;
  }
}

__global__ void k_padzero2(u16* __restrict__ XpH, u16* __restrict__ XpL){
  int i = blockIdx.x*256 + threadIdx.x;
  u16* P = (i >> 14) ? XpL : XpH;
  int ii = i & 16383;
  int b = ii >> 10, rr = (ii >> 8) & 3, c = ii & 255;
  int row = (rr < 2) ? rr : (2048 + rr);
  P[((size_t)b*2052 + row)*256 + c] = 0;
}

// EPI: 0 bias, 1 bias+cond, 2 tanh(acc+bias), 3 m+x1 fused flowmix + x0 passthrough (cnd = zsrc)
template<int EPI, int SPLITOUT>
__global__ __launch_bounds__(256,2) void k_mf2(
  const u16* __restrict__ Ah, const u16* __restrict__ Al, int lda, int padA,
  const u16* __restrict__ Bh, const u16* __restrict__ Bl, int ldb,
  const float* __restrict__ bias, const float* __restrict__ cnd,
  void* __restrict__ CH, void* __restrict__ CL, int ldc, int padC, int K)
{
  __shared__ u16 AsmH[4096], AsmL[4096], BsmH[4096], BsmL[4096];
  char* AHB=(char*)AsmH; char* ALB=(char*)AsmL;
  char* BHB=(char*)BsmH; char* BLB=(char*)BsmL;
  const int t = threadIdx.x;
  const int m0 = blockIdx.y << 7, n0 = blockIdx.x << 7;
  const int w = t >> 6, l = t & 63;
  const int wr = (w >> 1) << 6, wc = (w & 1) << 6;
  const int lr = l & 15, lg = l >> 4;
  const int srow = t >> 1, sseg = t & 1;
  const int q = (srow >> 1) & 3;
  const int wo0 = srow*64 + ((((sseg<<1)|0) ^ q) << 4);
  const int wo1 = srow*64 + ((((sseg<<1)|1) ^ q) << 4);
  const int am = m0 + srow;
  const size_t aoff = (size_t)(am + padA*(am >> 11))*lda + (sseg << 4);
  const u16* AhP = Ah + aoff;
  const u16* AlP = Al + aoff;
  const size_t boff = (size_t)(n0 + srow)*ldb + (sseg << 4);
  const u16* BhP = Bh + boff;
  const u16* BlP = Bl + boff;
  const int qa = ((wr + lr) >> 1) & 3, qb = ((wc + lr) >> 1) & 3;
  const int raBase = (wr + lr)*64 + ((lg ^ qa) << 4);
  const int rbBase = (wc + lr)*64 + ((lg ^ qb) << 4);
  f32x4 acc[4][4];
#pragma unroll
  for (int i=0;i<4;i++)
#pragma unroll
    for (int j=0;j<4;j++) acc[i][j] = (f32x4){0.f,0.f,0.f,0.f};

  float4 sah0, sah1, sal0, sal1, sbh0, sbh1, sbl0, sbl1;
  auto LOADF = [&](int kk){
    sah0 = *(const float4*)(AhP + kk); sah1 = *(const float4*)(AhP + kk + 8);
    sal0 = *(const float4*)(AlP + kk); sal1 = *(const float4*)(AlP + kk + 8);
    sbh0 = *(const float4*)(BhP + kk); sbh1 = *(const float4*)(BhP + kk + 8);
    sbl0 = *(const float4*)(BlP + kk); sbl1 = *(const float4*)(BlP + kk + 8);
  };

  LOADF(0);
  for (int k0 = 0; k0 < K; k0 += 32){
    __syncthreads();
    *(float4*)(AHB + wo0) = sah0;  *(float4*)(AHB + wo1) = sah1;
    *(float4*)(ALB + wo0) = sal0;  *(float4*)(ALB + wo1) = sal1;
    *(float4*)(BHB + wo0) = sbh0;  *(float4*)(BHB + wo1) = sbh1;
    *(float4*)(BLB + wo0) = sbl0;  *(float4*)(BLB + wo1) = sbl1;
    if (k0 + 32 < K) LOADF(k0 + 32);
    __syncthreads();
    short8v fah[4], fal[4], fbh[4], fbl[4];
#pragma unroll
    for (int i=0;i<4;i++){
      fah[i] = *(short8v*)(AHB + raBase + i*1024);
      fal[i] = *(short8v*)(ALB + raBase + i*1024);
    }
#pragma unroll
    for (int j=0;j<4;j++){
      fbh[j] = *(short8v*)(BHB + rbBase + j*1024);
      fbl[j] = *(short8v*)(BLB + rbBase + j*1024);
    }
#pragma unroll
    for (int i=0;i<4;i++)
#pragma unroll
      for (int j=0;j<4;j++){
        acc[i][j] = __builtin_amdgcn_mfma_f32_16x16x32_bf16(fah[i], fbh[j], acc[i][j], 0, 0, 0);
        acc[i][j] = __builtin_amdgcn_mfma_f32_16x16x32_bf16(fal[i], fbh[j], acc[i][j], 0, 0, 0);
        acc[i][j] = __builtin_amdgcn_mfma_f32_16x16x32_bf16(fah[i], fbl[j], acc[i][j], 0, 0, 0);
      }
  }

#pragma unroll
  for (int i=0;i<4;i++){
    int mbase = m0 + wr + i*16 + (lg << 2);
#pragma unroll
    for (int j=0;j<4;j++){
      int nn = n0 + wc + j*16 + lr;
      float bs = bias[nn];
      f32x4 v = acc[i][j];
#pragma unroll
      for (int r=0;r<4;r++){
        int m = mbase + r;
        float x = v[r] + bs;
        if (EPI == 1) x += cnd[((m >> 11) << 8) + nn];
        if (EPI == 2) x = tanhf(x);
        if (EPI == 3) x += cnd[(size_t)m*256 + 128 + nn];   // + x1
        size_t ro = (size_t)(m + padC*(m >> 11))*ldc + nn;
        if (SPLITOUT){
          u16 xh = f2bf(x);
          ((u16*)CH)[ro] = xh;
          ((u16*)CL)[ro] = f2bf(x - bf2f(xh));
        } else {
          ((float*)CH)[ro] = x;
          if (EPI == 3)
            ((float*)CH)[(size_t)m*ldc + 128 + nn] = cnd[(size_t)m*256 + nn];
        }
      }
    }
  }
}

// ---------------- MAS: single-wave phased double-group scan + prefetched backtrack ----------------
__device__ __forceinline__ void mas_row1(float4 u0, float4 u1, float* Q, int ln, int tr,
                                         unsigned char* __restrict__ cb){
  float v[8] = {u0.x,u0.y,u0.z,u0.w,u1.x,u1.y,u1.z,u1.w};
  float qp = __shfl_up(Q[7], 1);
  if (ln == 0) qp = NEGF;
  unsigned bits = 0; float qs = qp;
#pragma unroll
  for (int i=0;i<8;i++){
    float old = Q[i];
    if (qs > old) bits |= (1u<<i);
    Q[i] = v[i] + fmaxf(old, qs);
    qs = old;
  }
  cb[(size_t)(tr-1)*64 + ln] = (unsigned char)bits;
}

__global__ __launch_bounds__(64,1) void k_mas(const float* __restrict__ lp,
  const int* __restrict__ text, unsigned char* __restrict__ cho, int* __restrict__ path)
{
  const int b = blockIdx.x, ln = threadIdx.x;
  const float* L = lp + (size_t)b*TZ_*TT_;
  const float* Lr = L + ln*8;
  unsigned char* cb = cho + (size_t)b*TZ_*64;
  __shared__ __align__(16) unsigned char lch[3*4096];

  // ===== forward: phased double-group (A,B) register pipeline =====
  float Q[8];
#pragma unroll
  for (int i=0;i<8;i++) Q[i] = NEGF;
  if (ln == 0) Q[0] = L[0];

  float4 A0a,A0b,A1a,A1b,A2a,A2b,A3a,A3b,A4a,A4b,A5a,A5b,A6a,A6b,A7a,A7b;
  float4 B0a,B0b,B1a,B1b,B2a,B2b,B3a,B3b,B4a,B4b,B5a,B5b,B6a,B6b,B7a,B7b;
#define LDG(Pa, Pb, ROW) { const float* _s = Lr + (size_t)(ROW)*TT_; \
    Pa = *(const float4*)_s; Pb = *(const float4*)(_s + 4); }

  // prologue: groups at rows 1..8 (A) and 9..16 (B)
  LDG(A0a,A0b,1) LDG(A1a,A1b,2) LDG(A2a,A2b,3) LDG(A3a,A3b,4)
  LDG(A4a,A4b,5) LDG(A5a,A5b,6) LDG(A6a,A6b,7) LDG(A7a,A7b,8)
  LDG(B0a,B0b,9)  LDG(B1a,B1b,10) LDG(B2a,B2b,11) LDG(B3a,B3b,12)
  LDG(B4a,B4b,13) LDG(B5a,B5b,14) LDG(B6a,B6b,15) LDG(B7a,B7b,16)
  asm volatile("" ::: "memory");

  int gi = 1;
  for (; gi + 31 <= TZ_ - 1; gi += 16){
    // compute group A (rows gi..gi+7)
    mas_row1(A0a,A0b,Q,ln,gi+0,cb); mas_row1(A1a,A1b,Q,ln,gi+1,cb);
    mas_row1(A2a,A2b,Q,ln,gi+2,cb); mas_row1(A3a,A3b,Q,ln,gi+3,cb);
    mas_row1(A4a,A4b,Q,ln,gi+4,cb); mas_row1(A5a,A5b,Q,ln,gi+5,cb);
    mas_row1(A6a,A6b,Q,ln,gi+6,cb); mas_row1(A7a,A7b,Q,ln,gi+7,cb);
    // burst-load A's next rows (gi+16..gi+23); covered by compute of B
    LDG(A0a,A0b,gi+16) LDG(A1a,A1b,gi+17) LDG(A2a,A2b,gi+18) LDG(A3a,A3b,gi+19)
    LDG(A4a,A4b,gi+20) LDG(A5a,A5b,gi+21) LDG(A6a,A6b,gi+22) LDG(A7a,A7b,gi+23)
    asm volatile("" ::: "memory");
    // compute group B (rows gi+8..gi+15)
    mas_row1(B0a,B0b,Q,ln,gi+8,cb);  mas_row1(B1a,B1b,Q,ln,gi+9,cb);
    mas_row1(B2a,B2b,Q,ln,gi+10,cb); mas_row1(B3a,B3b,Q,ln,gi+11,cb);
    mas_row1(B4a,B4b,Q,ln,gi+12,cb); mas_row1(B5a,B5b,Q,ln,gi+13,cb);
    mas_row1(B6a,B6b,Q,ln,gi+14,cb); mas_row1(B7a,B7b,Q,ln,gi+15,cb);
    // burst-load B's next rows (gi+24..gi+31); covered by compute of A next iter
    LDG(B0a,B0b,gi+24) LDG(B1a,B1b,gi+25) LDG(B2a,B2b,gi+26) LDG(B3a,B3b,gi+27)
    LDG(B4a,B4b,gi+28) LDG(B5a,B5b,gi+29) LDG(B6a,B6b,gi+30) LDG(B7a,B7b,gi+31)
    asm volatile("" ::: "memory");
  }
#undef LDG
  // epilogue: regs hold rows gi..gi+15 (2017..2032)
  mas_row1(A0a,A0b,Q,ln,gi+0,cb); mas_row1(A1a,A1b,Q,ln,gi+1,cb);
  mas_row1(A2a,A2b,Q,ln,gi+2,cb); mas_row1(A3a,A3b,Q,ln,gi+3,cb);
  mas_row1(A4a,A4b,Q,ln,gi+4,cb); mas_row1(A5a,A5b,Q,ln,gi+5,cb);
  mas_row1(A6a,A6b,Q,ln,gi+6,cb); mas_row1(A7a,A7b,Q,ln,gi+7,cb);
  mas_row1(B0a,B0b,Q,ln,gi+8,cb);  mas_row1(B1a,B1b,Q,ln,gi+9,cb);
  mas_row1(B2a,B2b,Q,ln,gi+10,cb); mas_row1(B3a,B3b,Q,ln,gi+11,cb);
  mas_row1(B4a,B4b,Q,ln,gi+12,cb); mas_row1(B5a,B5b,Q,ln,gi+13,cb);
  mas_row1(B6a,B6b,Q,ln,gi+14,cb); mas_row1(B7a,B7b,Q,ln,gi+15,cb);
  for (int t = gi + 16; t < TZ_; t++){
    const float* s = Lr + (size_t)t*TT_;
    float4 a = *(const float4*)s;
    float4 c = *(const float4*)(s + 4);
    mas_row1(a, c, Q, ln, t, cb);
  }

  // ===== jlast =====
  int cnt = 0;
#pragma unroll
  for (int i=0;i<8;i++) cnt += (text[b*TT_ + ln*8 + i] != 0) ? 1 : 0;
#pragma unroll
  for (int o2=32;o2;o2>>=1) cnt += __shfl_xor(cnt, o2);
  const int jl = cnt - 1;
  if (ln == 0) path[b*TZ_ + TZ_-1] = jl;

  __syncthreads();   // single wave: drains cb stores before backtrack reads

  // ===== backtrack: positions p=0..2046 walk rows 2046-p; slot = 64 positions =====
  const int NP = TZ_ - 1;        // 2047
  uint* lchU = (uint*)lch;
  const uint* cbU = (const uint*)cb;
  {
    int r0 = 2046 - ln;
#pragma unroll
    for (int k=0;k<4;k++)
      *(u4v*)&lchU[0*1024 + ln*16 + k*4] = *(const u4v*)&cbU[(size_t)r0*16 + k*4];
    int r1 = 2046 - (64 + ln);
#pragma unroll
    for (int k=0;k<4;k++)
      *(u4v*)&lchU[1*1024 + ln*16 + k*4] = *(const u4v*)&cbU[(size_t)r1*16 + k*4];
  }
  u4v su0, su1, su2, su3;
  {
    int r2 = 2046 - (128 + ln);
    su0 = *(const u4v*)&cbU[(size_t)r2*16 + 0];
    su1 = *(const u4v*)&cbU[(size_t)r2*16 + 4];
    su2 = *(const u4v*)&cbU[(size_t)r2*16 + 8];
    su3 = *(const u4v*)&cbU[(size_t)r2*16 + 12];
  }

  int j = jl;
  unsigned rb0[8], rb1[8]; int rc[8];
  if (ln == 0){
#pragma unroll
    for (int qd=0; qd<8; qd++){
      int cHi = jl >> 3;
      int cLo = (cHi > 0) ? cHi - 1 : 0;
      rb1[qd] = lch[qd*64 + cHi];
      rb0[qd] = lch[qd*64 + cLo];
      rc[qd]  = cHi;
    }
  }
  for (int H = 0; H < 32; H++){
    if (H + 2 < 32){
      uint* wb = lchU + ((H+2)%3)*1024;
      *(u4v*)&wb[ln*16 + 0]  = su0;
      *(u4v*)&wb[ln*16 + 4]  = su1;
      *(u4v*)&wb[ln*16 + 8]  = su2;
      *(u4v*)&wb[ln*16 + 12] = su3;
    }
    if (H + 3 < 32){
      int p = (H+3)*64 + ln;
      if (p <= 2046){
        int r = 2046 - p;
        su0 = *(const u4v*)&cbU[(size_t)r*16 + 0];
        su1 = *(const u4v*)&cbU[(size_t)r*16 + 4];
        su2 = *(const u4v*)&cbU[(size_t)r*16 + 8];
        su3 = *(const u4v*)&cbU[(size_t)r*16 + 12];
      }
    }
    if (ln == 0){
      int pbase = H*64;
#pragma unroll 8
      for (int s = 0; s < 64; s++){
        int p = pbase + s;
        if (p < NP){
          int r = s & 7;
          int jb = j >> 3;
          unsigned byte = (jb == rc[r]) ? rb1[r] : rb0[r];
          j -= (int)((byte >> (j & 7)) & 1u);
          path[b*TZ_ + 2046 - p] = j;
          int pn = p + 8;
          if (pn < NP){
            int hn = (pn >> 6) % 3, sn = pn & 63;
            int cHi = j >> 3;
            int cLo = (cHi > 0) ? cHi - 1 : 0;
            rb1[r] = lch[hn*4096 + sn*64 + cHi];
            rb0[r] = lch[hn*4096 + sn*64 + cLo];
            rc[r]  = cHi;
          }
        }
      }
    }
    __syncthreads();
  }
}

// ---------------- ctx gather + h copy ----------------
__global__ void k_gather(const float* __restrict__ mulv, const int* __restrict__ path,
  const float* __restrict__ h, float* __restrict__ out){
  size_t i = (size_t)blockIdx.x*256 + threadIdx.x;
  const size_t N4 = (size_t)BB*TZ_*(D_/4);
  const size_t H4 = (size_t)BB*TT_*(D_/4);
  if (i < N4){
    size_t row = i >> 6; int c = (int)(i & 63);
    int b = (int)(row >> 11);
    int pj = path[row];
    ((float4*)out)[i] = *(const float4*)(mulv + ((size_t)b*TT_ + pj)*512 + (size_t)c*4);
  } else if (i < N4 + H4){
    size_t k2 = i - N4;
    ((float4*)out)[i] = ((const float4*)h)[k2];
  }
}

extern "C" void kernel_launch(void* const* d_in, const int* in_sizes, int n_in,
                              void* d_out, int out_size, void* d_ws, size_t ws_size,
                              hipStream_t stream)
{
  (void)in_sizes; (void)n_in; (void)out_size; (void)ws_size;
  const float* z      = (const float*)d_in[0];
  const int*   text   = (const int*)  d_in[1];
  const float* cond   = (const float*)d_in[2];
  const float* emb    = (const float*)d_in[3];
  const float* wq     = (const float*)d_in[4];
  const float* wk     = (const float*)d_in[5];
  const float* wv     = (const float*)d_in[6];
  const float* wo     = (const float*)d_in[7];
  const float* bq     = (const float*)d_in[8];
  const float* bk     = (const float*)d_in[9];
  const float* bv     = (const float*)d_in[10];
  const float* bo     = (const float*)d_in[11];
  const float* ln1g   = (const float*)d_in[12];
  const float* ln1b   = (const float*)d_in[13];
  const float* ln2g   = (const float*)d_in[14];
  const float* ln2b   = (const float*)d_in[15];
  const float* w1     = (const float*)d_in[16];
  const float* b1     = (const float*)d_in[17];
  const float* w2     = (const float*)d_in[18];
  const float* b2     = (const float*)d_in[19];
  const float* mu_w   = (const float*)d_in[20];
  const float* mu_b   = (const float*)d_in[21];
  const float* lv_w   = (const float*)d_in[22];
  const float* lv_b   = (const float*)d_in[23];
  const float* f_in   = (const float*)d_in[24];
  const float* f_in_b = (const float*)d_in[25];
  const float* f_cond = (const float*)d_in[26];
  const float* f_conv = (const float*)d_in[27];
  const float* f_convb= (const float*)d_in[28];
  const float* f_out  = (const float*)d_in[29];
  const float* f_outb = (const float*)d_in[30];

  // ---- workspace: 59,297,792 floats = 237,191,168 B (proven size) ----
  float* ws = (float*)d_ws;
  size_t o = 0;
  float* PE   = ws + o; o += (size_t)131072;
  float* H    = ws + o; o += (size_t)2097152;
  float* MULV = ws + o; o += (size_t)4194304;
  float* NC1  = ws + o; o += (size_t)8192;
  float* NC4  = ws + o; o += (size_t)8192;
  float* CONDP= ws + o; o += (size_t)4096;
  int*   PATH = (int*)(ws + o); o += (size_t)32768;
  u16*  B2H  = (u16*)(ws + o); o += (size_t)2097152;
  u16*  B2L  = (u16*)(ws + o); o += (size_t)2097152;
  float* BIGS = ws + o; o += (size_t)16777216;
  float* BUF1 = ws + o; o += (size_t)4587520;
  float* BUF2 = ws + o; o += (size_t)10485760;
  float* ZCA  = ws + o; o += (size_t)8388608;
  float* ZCB  = ws + o; o += (size_t)8388608;

  float* QKV = BUF2;
  float* Yb  = QKV + 6291456;
  float* VT  = Yb + 2097152;
  float* ATTO= QKV;
  float* QKVT = ZCA;
  float* OT   = QKVT + 1179648;
  float* W1T  = OT + 393216;
  float* W2T  = W1T + 1572864;
  float* MULVT= W2T + 1572864;
  float* BQKV = MULVT + 131072;
  float* MULVB= BQKV + 4608;
  u16*  X0H = (u16*)BUF1;
  u16*  X0L = X0H + 4194304;
  u16*  WITH = X0L + 4194304;
  u16*  WITL = WITH + 32768;
  u16*  WCTH = WITL + 32768;
  u16*  WCTL = WCTH + 327680;
  u16*  WOTH = WCTL + 327680;
  u16*  WOTL = WOTH + 32768;
  u16*  XpH = (u16*)BIGS;
  u16*  XpL = XpH + 8404992;
  u16*  H2H = (u16*)BUF2;
  u16*  H2L = H2H + 8388608;
  unsigned char* CHO = (unsigned char*)ZCA;

  k_pe   <<<dim3(TT_),    dim3(D_), 0, stream>>>(PE);
  k_embed<<<dim3(BB*TT_), dim3(D_), 0, stream>>>(text, emb, PE, H);
  k_wt   <<<dim3(16,74), 256, 0, stream>>>(wq,wk,wv,wo,mu_w,lv_w,w1,w2, QKVT,OT,MULVT,W1T,W2T);
  k_bcat <<<dim3(20), 256, 0, stream>>>(bq,bk,bv,mu_b,lv_b, BQKV, MULVB);

  for (int l=0;l<L_;l++){
    k_mg<4,0,0,0><<<dim3(6,64,1),256,0,stream>>>(
      H, nullptr, 256, 0,0,  QKVT + (size_t)l*196608, nullptr, 256, 0,0,
      BQKV + l*768, nullptr, nullptr, nullptr, QKV, 768, 0,0, 256);
    k_vt <<<dim3(4,8,16),256,0,stream>>>(QKV, VT);
    k_mg<4,2,0,0><<<dim3(4,4,64),256,0,stream>>>(
      QKV, nullptr, 768, 393216, 64,  QKV+256, nullptr, 768, 393216, 64,
      nullptr, text, nullptr, nullptr, BIGS, 512, 1048576, 262144, 64);
    k_softmax<<<dim3(BB*HEADS_*TT_/4),256,0,stream>>>(BIGS);
    k_mg<2,0,0,0><<<dim3(1,4,64),256,0,stream>>>(
      BIGS, nullptr, 512, 1048576, 262144,  VT, nullptr, 512, 131072, 32768,
      nullptr, nullptr, nullptr, nullptr, Yb, 256, 131072, 64, 512);
    k_mg<4,0,0,0><<<dim3(2,64,1),256,0,stream>>>(
      Yb, nullptr, 256, 0,0,  OT + (size_t)l*65536, nullptr, 256, 0,0,
      bo + l*256, nullptr, nullptr, nullptr, ATTO, 256, 0,0, 256);
    k_lnres<<<dim3(BB*TT_),256,0,stream>>>(ATTO, ln1g+l*D_, ln1b+l*D_, H);
    k_mg<4,1,0,0><<<dim3(8,64,1),256,0,stream>>>(
      H, nullptr, 256, 0,0,  W1T + (size_t)l*262144, nullptr, 256, 0,0,
      b1 + l*1024, nullptr, nullptr, nullptr, BIGS, 1024, 0,0, 256);
    k_mg<4,0,0,0><<<dim3(2,64,1),256,0,stream>>>(
      BIGS, nullptr, 1024, 0,0,  W2T + (size_t)l*262144, nullptr, 1024, 0,0,
      b2 + l*256, nullptr, nullptr, nullptr, ATTO, 256, 0,0, 1024);
    k_lnres<<<dim3(BB*TT_),256,0,stream>>>(ATTO, ln2g+l*D_, ln2b+l*D_, H);
  }

  k_mg<4,0,0,0><<<dim3(4,64,1),256,0,stream>>>(
    H, nullptr, 256, 0,0,  MULVT, nullptr, 256, 0,0,
    MULVB, nullptr, nullptr, nullptr, MULV, 512, 0,0, 256);
  k_prep<<<dim3(BB*TT_),256,0,stream>>>(MULV, B2H, B2L, NC1, NC4);

  // ---- flows ----
  k_padzero2<<<dim3(128),256,0,stream>>>(XpH, XpL);
  const float* zsrc = z;
  for (int f=0; f<FLOWS_; f++){
    k_fprep<<<dim3(3600),256,0,stream>>>(
        f_in + (size_t)f*(CH_/2)*HID_, f_conv + (size_t)f*KCV*HID_*HID_,
        f_out + (size_t)f*HID_*(CH_/2),
        WITH, WITL, WCTH, WCTL, WOTH, WOTL,
        zsrc, X0H, X0L,
        cond, f_cond + (size_t)f*G_*HID_, CONDP);
    k_mf2<1,1><<<dim3(2,256),256,0,stream>>>(X0H, X0L, 128, 0, WITH, WITL, 128,
        f_in_b + f*HID_, CONDP, (void*)(XpH + 512), (void*)(XpL + 512), 256, 4, 128);
    k_mf2<2,1><<<dim3(2,256),256,0,stream>>>(XpH, XpL, 256, 4, WCTH, WCTL, 1280,
        f_convb + f*HID_, nullptr, (void*)H2H, (void*)H2L, 256, 0, 1280);
    float* zdst = (f & 1) ? ZCB : ZCA;
    k_mf2<3,0><<<dim3(1,256),256,0,stream>>>(H2H, H2L, 256, 0, WOTH, WOTL, 256,
        f_outb + f*(CH_/2), zsrc, (void*)zdst, nullptr, 256, 0, 256);
    zsrc = zdst;
  }

  // logp
  k_mg<4,3,2,1><<<dim3(4,16,16),256,0,stream>>>(
    zsrc, nullptr, 256, 2097152, 524288,
    B2H, B2L, 512, 1048576, 262144,
    nullptr, text, NC1, NC4, BIGS, 512, 4194304, 1048576, 512);

  k_mas<<<dim3(BB),64,0,stream>>>(BIGS, text, CHO, PATH);
  k_gather<<<dim3((BB*TZ_*D_/4 + BB*TT_*D_/4)/256),256,0,stream>>>(MULV, PATH, H, (float*)d_out);
}

// Round 13
// 2155.056 us; speedup vs baseline: 1.0324x; 1.0324x over previous
//
#include <hip/hip_runtime.h>

#define BB 16
#define TZ_ 2048
#define TT_ 512
#define D_ 256
#define DFF_ 1024
#define L_ 6
#define HEADS_ 4
#define DH_ 64
#define CH_ 256
#define HID_ 256
#define KCV 5
#define FLOWS_ 4
#define G_ 256
#define NEGF (-1000000000.0f)
#define LOG2PI 1.8378770664093453f

typedef unsigned short u16;
typedef __attribute__((ext_vector_type(8))) short short8v;
typedef __attribute__((ext_vector_type(4))) float f32x4;
typedef __attribute__((ext_vector_type(4))) unsigned u4v;

__device__ __forceinline__ float wsum(float v){
#pragma unroll
  for (int o = 32; o; o >>= 1) v += __shfl_xor(v, o);
  return v;
}
__device__ __forceinline__ u16 f2bf(float x){
  unsigned u = __float_as_uint(x);
  return (u16)((u + 0x7FFFu + ((u >> 16) & 1u)) >> 16);
}
__device__ __forceinline__ float bf2f(u16 h){
  return __uint_as_float(((unsigned)h) << 16);
}
__device__ __forceinline__ unsigned pk2f(float a, float b){
  return __builtin_amdgcn_perm(__float_as_uint(b), __float_as_uint(a), 0x07060302u);
}
__device__ __forceinline__ float trnc(float f){
  return __uint_as_float(__float_as_uint(f) & 0xFFFF0000u);
}
__device__ __forceinline__ void cvt8t(float4 x, float4 y, uint4 &hi, uint4 &lo){
  hi.x = pk2f(x.x, x.y); hi.y = pk2f(x.z, x.w);
  hi.z = pk2f(y.x, y.y); hi.w = pk2f(y.z, y.w);
  float r0 = x.x - trnc(x.x), r1 = x.y - trnc(x.y), r2 = x.z - trnc(x.z), r3 = x.w - trnc(x.w);
  float r4 = y.x - trnc(y.x), r5 = y.y - trnc(y.y), r6 = y.z - trnc(y.z), r7 = y.w - trnc(y.w);
  lo.x = pk2f(r0, r1); lo.y = pk2f(r2, r3); lo.z = pk2f(r4, r5); lo.w = pk2f(r6, r7);
}
__device__ __forceinline__ unsigned rneh(float f){
  unsigned v = __float_as_uint(f);
  return (v + 0x7FFFu + ((v >> 16) & 1u)) & 0xFFFF0000u;
}
__device__ __forceinline__ void cvt8r(float4 x, float4 y, uint4 &hi, uint4 &lo){
  unsigned h0=rneh(x.x), h1=rneh(x.y), h2=rneh(x.z), h3=rneh(x.w);
  unsigned h4=rneh(y.x), h5=rneh(y.y), h6=rneh(y.z), h7=rneh(y.w);
  hi.x = h1 | (h0>>16); hi.y = h3 | (h2>>16); hi.z = h5 | (h4>>16); hi.w = h7 | (h6>>16);
  float r0 = x.x - __uint_as_float(h0), r1 = x.y - __uint_as_float(h1);
  float r2 = x.z - __uint_as_float(h2), r3 = x.w - __uint_as_float(h3);
  float r4 = y.x - __uint_as_float(h4), r5 = y.y - __uint_as_float(h5);
  float r6 = y.z - __uint_as_float(h6), r7 = y.w - __uint_as_float(h7);
  lo.x = pk2f(r0, r1); lo.y = pk2f(r2, r3); lo.z = pk2f(r4, r5); lo.w = pk2f(r6, r7);
}

// ---------------- positional encoding ----------------
__global__ void k_pe(float* __restrict__ pe){
  int t = blockIdx.x, d = threadIdx.x;
  double e = (double)(2*(d>>1)) / (double)D_;
  double ang = (double)t * pow(10000.0, -e);
  pe[t*D_ + d] = (float)(((d&1)==0) ? sin(ang) : cos(ang));
}
// ---------------- embedding ----------------
__global__ void k_embed(const int* __restrict__ text, const float* __restrict__ emb,
                        const float* __restrict__ pe, float* __restrict__ h){
  int row = blockIdx.x, d = threadIdx.x;
  h[(size_t)row*D_ + d] = emb[(size_t)text[row]*D_ + d]*16.0f + pe[(row%TT_)*D_ + d];
}

// ---------------- weight transposes (74 slots of 256x256) ----------------
__global__ __launch_bounds__(256) void k_wt(
  const float* __restrict__ wq, const float* __restrict__ wk,
  const float* __restrict__ wv, const float* __restrict__ wo,
  const float* __restrict__ mu_w, const float* __restrict__ lv_w,
  const float* __restrict__ w1, const float* __restrict__ w2,
  float* __restrict__ QKVT, float* __restrict__ OT, float* __restrict__ MULVT,
  float* __restrict__ W1T, float* __restrict__ W2T)
{
  __shared__ float td[64][65];
  const int s = blockIdx.y, tile = blockIdx.x, t = threadIdx.x;
  const float* inb; float* outb; int istride, ostride;
  if (s < 24){
    int l = s>>2, wsel = s&3;
    const float* w = (wsel==0?wq:wsel==1?wk:wsel==2?wv:wo);
    inb = w + (size_t)l*65536; istride = 256;
    if (wsel < 3) outb = QKVT + (size_t)l*196608 + wsel*65536;
    else          outb = OT   + (size_t)l*65536;
    ostride = 256;
  } else if (s < 26){
    inb = (s==24 ? mu_w : lv_w); istride = 256;
    outb = MULVT + (size_t)(s-24)*65536; ostride = 256;
  } else if (s < 50){
    int idx = s-26, l = idx>>2, b2 = idx&3;
    inb = w1 + (size_t)l*262144 + b2*256; istride = 1024;
    outb = W1T + (size_t)l*262144 + (size_t)b2*65536; ostride = 256;
  } else {
    int idx = s-50, l = idx>>2, b2 = idx&3;
    inb = w2 + (size_t)l*262144 + (size_t)b2*65536; istride = 256;
    outb = W2T + (size_t)l*262144 + b2*256; ostride = 1024;
  }
  const int kt = (tile>>2)*64, nt = (tile&3)*64;
  const int r = t>>2, cq = (t&3)*16;
#pragma unroll
  for (int c=0;c<16;c+=4){
    float4 v = *(const float4*)(inb + (size_t)(kt + r)*istride + nt + cq + c);
    td[r][cq+c+0]=v.x; td[r][cq+c+1]=v.y; td[r][cq+c+2]=v.z; td[r][cq+c+3]=v.w;
  }
  __syncthreads();
#pragma unroll
  for (int c=0;c<16;c+=4){
    float4 v = make_float4(td[cq+c+0][r], td[cq+c+1][r], td[cq+c+2][r], td[cq+c+3][r]);
    *(float4*)(outb + (size_t)(nt + r)*ostride + kt + cq + c) = v;
  }
}

// ---------------- V transpose per layer ----------------
__global__ __launch_bounds__(256) void k_vt(const float* __restrict__ QKV, float* __restrict__ VT){
  __shared__ float td[64][65];
  const int b = blockIdx.z, dt = blockIdx.x, jt = blockIdx.y, t = threadIdx.x;
  const float* inb = QKV + (size_t)b*512*768 + 512;
  float* outb = VT + (size_t)b*131072;
  const int r = t>>2, cq = (t&3)*16;
#pragma unroll
  for (int c=0;c<16;c+=4){
    float4 v = *(const float4*)(inb + (size_t)(jt*64 + r)*768 + dt*64 + cq + c);
    td[r][cq+c+0]=v.x; td[r][cq+c+1]=v.y; td[r][cq+c+2]=v.z; td[r][cq+c+3]=v.w;
  }
  __syncthreads();
#pragma unroll
  for (int c=0;c<16;c+=4){
    float4 v = make_float4(td[cq+c+0][r], td[cq+c+1][r], td[cq+c+2][r], td[cq+c+3][r]);
    *(float4*)(outb + (size_t)(dt*64 + r)*512 + jt*64 + cq + c) = v;
  }
}

// ---------------- bias concat ----------------
__global__ void k_bcat(const float* __restrict__ bq, const float* __restrict__ bk,
                       const float* __restrict__ bv, const float* __restrict__ mu_b,
                       const float* __restrict__ lv_b,
                       float* __restrict__ BQKV, float* __restrict__ MULVB){
  int i = blockIdx.x*256 + threadIdx.x;
  if (i < 4608){
    int l = i/768, c = i%768;
    float v = c<256 ? bq[l*256+c] : (c<512 ? bk[l*256+c-256] : bv[l*256+c-512]);
    BQKV[i] = v;
  } else if (i < 5120){
    int c = i-4608;
    MULVB[c] = c<256 ? mu_b[c] : lv_b[c-256];
  }
}

// =========== universal split-bf16 MFMA GEMM (software-pipelined K loop) ===========
// AM: 0 f32 trunc-split, 1 presplit u16, 2 [zc|-0.5zc^2] (rne), 4 softmax-normalized f32
//     (AM==4: nc1v = row max array, nc4v = row inv-sum array, row = z*TT_ + m0 + srow)
template<int WN, int EPI, int AM, int BMD>
__global__ __launch_bounds__(256,2) void k_mg(
  const void* __restrict__ Ap, const void* __restrict__ ApL, int lda, int azhi, int azlo,
  const void* __restrict__ Bp, const void* __restrict__ BpL, int ldb, int bzhi, int bzlo,
  const float* __restrict__ bias, const int* __restrict__ text,
  const float* __restrict__ nc1v, const float* __restrict__ nc4v,
  float* __restrict__ C, int ldc, int czhi, int czlo, int K)
{
  constexpr int BN = WN*32;
  __shared__ u16 AH[4096], AL[4096];
  __shared__ u16 BH[BN*32], BL[BN*32];
  char* AHB=(char*)AH; char* ALB=(char*)AL; char* BHB=(char*)BH; char* BLB=(char*)BL;
  const int t = threadIdx.x, z = blockIdx.z;
  const int m0 = blockIdx.y*128, n0 = blockIdx.x*BN;
  const size_t aoff = (size_t)(z>>2)*azhi + (size_t)(z&3)*azlo;
  const size_t boff = (size_t)(z>>2)*bzhi + (size_t)(z&3)*bzlo;
  const size_t coff = (size_t)(z>>2)*czhi + (size_t)(z&3)*czlo;
  const int w = t>>6, l = t&63;
  const int wr = (w>>1)*64, wc = (w&1)*(WN*16);
  const int lr = l&15, lg = l>>4;
  const int srow = t>>1, sseg = t&1;
  const int q  = (srow>>1)&3;
  const int wo0 = srow*64 + ((((sseg<<1)|0)^q)<<4);
  const int wo1 = srow*64 + ((((sseg<<1)|1)^q)<<4);
  const bool bact = (WN==4) || (t < 128);
  const int qa = ((wr+lr)>>1)&3, qb2 = ((wc+lr)>>1)&3;
  const int raBase = (wr+lr)*64 + ((lg^qa)<<4);
  const int rbBase = (wc+lr)*64 + ((lg^qb2)<<4);

  const float* Af = nullptr; const u16* AfH = nullptr; const u16* AfL = nullptr;
  if constexpr (AM==0 || AM==2 || AM==4){ Af = (const float*)Ap + aoff; }
  else { AfH = (const u16*)Ap + aoff; AfL = (const u16*)ApL + aoff; }
  const float* Bf = nullptr; const u16* BfH = nullptr; const u16* BfL = nullptr;
  if constexpr (BMD==0){ Bf = (const float*)Bp + boff; }
  else { BfH = (const u16*)Bp + boff; BfL = (const u16*)BpL + boff; }

  float mrow = 0.f, sinv = 0.f;
  if constexpr (AM==4){
    int rg = z*TT_ + m0 + srow;
    mrow = nc1v[rg];
    sinv = nc4v[rg];
  }

  float4 sa0, sa1, sa2, sa3;
  uint4  pah0, pah1, pal0, pal1;
  float4 sb0, sb1, sb2, sb3;
  uint4  pbh0, pbh1, pbl0, pbl1;

  auto LOADA = [&](int kk){
    if constexpr (AM==0 || AM==4){
      const float* p = Af + (size_t)(m0+srow)*lda + kk + sseg*16;
      sa0=*(const float4*)p; sa1=*(const float4*)(p+4);
      sa2=*(const float4*)(p+8); sa3=*(const float4*)(p+12);
    } else if constexpr (AM==1){
      const u16* ph = AfH + (size_t)(m0+srow)*lda + kk + sseg*16;
      const u16* pl = AfL + (size_t)(m0+srow)*lda + kk + sseg*16;
      pah0 = *(const uint4*)ph; pah1 = *(const uint4*)(ph+8);
      pal0 = *(const uint4*)pl; pal1 = *(const uint4*)(pl+8);
    } else {
      int kg = kk + sseg*16;
      const float* p = Af + (size_t)(m0+srow)*lda + (kg < 256 ? kg : kg - 256);
      sa0=*(const float4*)p; sa1=*(const float4*)(p+4);
      sa2=*(const float4*)(p+8); sa3=*(const float4*)(p+12);
    }
  };
  auto LOADB = [&](int kk){
    if constexpr (BMD==0){
      const float* p = Bf + (size_t)(n0+srow)*ldb + kk + sseg*16;
      sb0=*(const float4*)p; sb1=*(const float4*)(p+4);
      sb2=*(const float4*)(p+8); sb3=*(const float4*)(p+12);
    } else {
      const u16* ph = BfH + (size_t)(n0+srow)*ldb + kk + sseg*16;
      const u16* pl = BfL + (size_t)(n0+srow)*ldb + kk + sseg*16;
      pbh0 = *(const uint4*)ph; pbh1 = *(const uint4*)(ph+8);
      pbl0 = *(const uint4*)pl; pbl1 = *(const uint4*)(pl+8);
    }
  };
  auto WRITEA = [&](int kk){
    uint4 ahi0, ahi1, alo0, alo1;
    if constexpr (AM==0){
      cvt8t(sa0,sa1,ahi0,alo0); cvt8t(sa2,sa3,ahi1,alo1);
    } else if constexpr (AM==4){
      float4 a0=sa0, a1=sa1, a2=sa2, a3=sa3;
      a0.x=expf(a0.x-mrow)*sinv; a0.y=expf(a0.y-mrow)*sinv; a0.z=expf(a0.z-mrow)*sinv; a0.w=expf(a0.w-mrow)*sinv;
      a1.x=expf(a1.x-mrow)*sinv; a1.y=expf(a1.y-mrow)*sinv; a1.z=expf(a1.z-mrow)*sinv; a1.w=expf(a1.w-mrow)*sinv;
      a2.x=expf(a2.x-mrow)*sinv; a2.y=expf(a2.y-mrow)*sinv; a2.z=expf(a2.z-mrow)*sinv; a2.w=expf(a2.w-mrow)*sinv;
      a3.x=expf(a3.x-mrow)*sinv; a3.y=expf(a3.y-mrow)*sinv; a3.z=expf(a3.z-mrow)*sinv; a3.w=expf(a3.w-mrow)*sinv;
      cvt8t(a0,a1,ahi0,alo0); cvt8t(a2,a3,ahi1,alo1);
    } else if constexpr (AM==1){
      ahi0=pah0; ahi1=pah1; alo0=pal0; alo1=pal1;
    } else {
      float4 a0=sa0, a1=sa1, a2=sa2, a3=sa3;
      int kg = kk + sseg*16;
      if (kg >= 256){
        a0.x=-0.5f*a0.x*a0.x; a0.y=-0.5f*a0.y*a0.y; a0.z=-0.5f*a0.z*a0.z; a0.w=-0.5f*a0.w*a0.w;
        a1.x=-0.5f*a1.x*a1.x; a1.y=-0.5f*a1.y*a1.y; a1.z=-0.5f*a1.z*a1.z; a1.w=-0.5f*a1.w*a1.w;
        a2.x=-0.5f*a2.x*a2.x; a2.y=-0.5f*a2.y*a2.y; a2.z=-0.5f*a2.z*a2.z; a2.w=-0.5f*a2.w*a2.w;
        a3.x=-0.5f*a3.x*a3.x; a3.y=-0.5f*a3.y*a3.y; a3.z=-0.5f*a3.z*a3.z; a3.w=-0.5f*a3.w*a3.w;
      }
      cvt8r(a0,a1,ahi0,alo0); cvt8r(a2,a3,ahi1,alo1);
    }
    *(uint4*)(AHB + wo0) = ahi0;  *(uint4*)(AHB + wo1) = ahi1;
    *(uint4*)(ALB + wo0) = alo0;  *(uint4*)(ALB + wo1) = alo1;
  };
  auto WRITEB = [&](){
    uint4 bhi0, bhi1, blo0, blo1;
    if constexpr (BMD==0){
      cvt8t(sb0,sb1,bhi0,blo0); cvt8t(sb2,sb3,bhi1,blo1);
    } else {
      bhi0=pbh0; bhi1=pbh1; blo0=pbl0; blo1=pbl1;
    }
    *(uint4*)(BHB + wo0) = bhi0;  *(uint4*)(BHB + wo1) = bhi1;
    *(uint4*)(BLB + wo0) = blo0;  *(uint4*)(BLB + wo1) = blo1;
  };

  f32x4 acc[4][WN];
#pragma unroll
  for (int i=0;i<4;i++)
#pragma unroll
    for (int j=0;j<WN;j++) acc[i][j] = (f32x4){0.f,0.f,0.f,0.f};

  LOADA(0);
  if (bact) LOADB(0);
  for (int k0 = 0; k0 < K; k0 += 32){
    __syncthreads();
    WRITEA(k0);
    if (bact) WRITEB();
    if (k0 + 32 < K){ LOADA(k0+32); if (bact) LOADB(k0+32); }
    __syncthreads();
    short8v fah[4], fal[4], fbh[WN], fbl[WN];
#pragma unroll
    for (int i=0;i<4;i++){
      fah[i] = *(short8v*)(AHB + raBase + i*1024);
      fal[i] = *(short8v*)(ALB + raBase + i*1024);
    }
#pragma unroll
    for (int j=0;j<WN;j++){
      fbh[j] = *(short8v*)(BHB + rbBase + j*1024);
      fbl[j] = *(short8v*)(BLB + rbBase + j*1024);
    }
#pragma unroll
    for (int i=0;i<4;i++)
#pragma unroll
      for (int j=0;j<WN;j++){
        acc[i][j] = __builtin_amdgcn_mfma_f32_16x16x32_bf16(fah[i], fbh[j], acc[i][j], 0,0,0);
        acc[i][j] = __builtin_amdgcn_mfma_f32_16x16x32_bf16(fal[i], fbh[j], acc[i][j], 0,0,0);
        acc[i][j] = __builtin_amdgcn_mfma_f32_16x16x32_bf16(fah[i], fbl[j], acc[i][j], 0,0,0);
      }
  }

#pragma unroll
  for (int i=0;i<4;i++){
    int mm0 = m0 + wr + i*16 + (lg<<2);
#pragma unroll
    for (int j=0;j<WN;j++){
      int nn = n0 + wc + j*16 + lr;
      float bs = 0.f; float ncb = 0.f; bool msk = true;
      if (EPI==0 || EPI==1) bs = bias ? bias[nn] : 0.f;
      if (EPI==2) msk = (text[(z>>2)*TT_ + nn] != 0);
      if (EPI==3){ ncb = nc1v[z*TT_+nn] + nc4v[z*TT_+nn]; msk = (text[z*TT_+nn] != 0); }
      f32x4 v = acc[i][j];
#pragma unroll
      for (int r=0;r<4;r++){
        int m = mm0 + r;
        float x;
        if (EPI==0)      x = v[r] + bs;
        else if (EPI==1) x = fmaxf(v[r] + bs, 0.f);
        else if (EPI==2) x = v[r]*0.125f + (msk ? 0.f : NEGF);
        else             x = msk ? (v[r] + ncb) : NEGF;
        C[coff + (size_t)m*ldc + nn] = x;
      }
    }
  }
}

// ---------------- row stats over 512 (4 rows per block): m and 1/sum ----------------
__global__ __launch_bounds__(256) void k_rowstat(const float* __restrict__ S,
  float* __restrict__ MR, float* __restrict__ SR){
  size_t row = (size_t)blockIdx.x*4 + (threadIdx.x >> 6);
  const float* p = S + row*TT_;
  int ln = threadIdx.x & 63;
  float4 a = *(const float4*)(p + ln*8);
  float4 b = *(const float4*)(p + ln*8 + 4);
  float x[8] = {a.x,a.y,a.z,a.w,b.x,b.y,b.z,b.w};
  float m = x[0];
#pragma unroll
  for (int i=1;i<8;i++) m = fmaxf(m, x[i]);
#pragma unroll
  for (int o2=32;o2;o2>>=1) m = fmaxf(m, __shfl_xor(m, o2));
  float s = 0.f;
#pragma unroll
  for (int i=0;i<8;i++){ s += expf(x[i]-m); }
  s = wsum(s);
  if (ln == 0){
    MR[row] = m;
    SR[row] = 1.0f/s;
  }
}

// ---------------- residual + LayerNorm ----------------
__global__ __launch_bounds__(256) void k_lnres(const float* __restrict__ y,
  const float* __restrict__ g, const float* __restrict__ bb, float* __restrict__ h){
  size_t row = blockIdx.x; int d = threadIdx.x;
  float v = h[row*D_ + d] + y[row*D_ + d];
  float s = wsum(v), s2 = wsum(v*v);
  __shared__ float r1[4], r2[4];
  int w = d >> 6;
  if ((d & 63) == 0){ r1[w] = s; r2[w] = s2; }
  __syncthreads();
  s  = r1[0]+r1[1]+r1[2]+r1[3];
  s2 = r2[0]+r2[1]+r2[2]+r2[3];
  float mean = s * (1.0f/D_);
  float var  = s2 * (1.0f/D_) - mean*mean;
  float inv  = rsqrtf(var + 1e-6f);
  h[row*D_ + d] = g[d]*(v - mean)*inv + bb[d];
}

// ---------------- prep: nc1/nc4 + B2 split planes [msp | spr] ----------------
__global__ __launch_bounds__(256) void k_prep(const float* __restrict__ mulv,
  u16* __restrict__ b2h, u16* __restrict__ b2l,
  float* __restrict__ nc1, float* __restrict__ nc4){
  size_t row = blockIdx.x; int d = threadIdx.x;
  float m = mulv[row*512 + d];
  float lv = mulv[row*512 + 256 + d];
  float sp = expf(-lv);
  float ms = m*sp;
  float s1 = wsum(lv), s2 = wsum(m*ms);
  __shared__ float r1[4], r2[4];
  int w = d >> 6;
  if ((d&63)==0){ r1[w]=s1; r2[w]=s2; }
  __syncthreads();
  if (d == 0){
    nc1[row] = -0.5f*((float)D_*LOG2PI + (r1[0]+r1[1]+r1[2]+r1[3]));
    nc4[row] = -0.5f*(r2[0]+r2[1]+r2[2]+r2[3]);
  }
  unsigned hm = rneh(ms);
  b2h[row*512 + d] = (u16)(hm>>16);
  b2l[row*512 + d] = f2bf(ms - __uint_as_float(hm));
  unsigned hs = rneh(sp);
  b2h[row*512 + 256 + d] = (u16)(hs>>16);
  b2l[row*512 + 256 + d] = f2bf(sp - __uint_as_float(hs));
}

// ---------------- fused per-flow prep: wprep + x0prep + condproj ----------------
__global__ __launch_bounds__(256) void k_fprep(
  const float* __restrict__ win, const float* __restrict__ wconv, const float* __restrict__ wout,
  u16* __restrict__ WITH, u16* __restrict__ WITL,
  u16* __restrict__ WCTH, u16* __restrict__ WCTL,
  u16* __restrict__ WOTH, u16* __restrict__ WOTL,
  const float* __restrict__ zsrc, u16* __restrict__ xh, u16* __restrict__ xl,
  const float* __restrict__ cond, const float* __restrict__ fcw, float* __restrict__ condp)
{
  const int bid = blockIdx.x, t = threadIdx.x;
  if (bid < 1536){
    int i = bid*256 + t;
    float wv2; u16 *dh, *dl; int idx;
    if (i < 32768){
      int n = i >> 7, k = i & 127;
      wv2 = win[k*256 + n]; dh = WITH; dl = WITL; idx = i;
    } else if (i < 360448){
      int jj = i - 32768;
      int o = jj / 1280, r = jj - o*1280;
      wv2 = wconv[(size_t)r*256 + o]; dh = WCTH; dl = WCTL; idx = jj;
    } else {
      int jj = i - 360448;
      int o = jj >> 8, k = jj & 255;
      wv2 = wout[k*128 + o]; dh = WOTH; dl = WOTL; idx = jj;
    }
    u16 hh = f2bf(wv2);
    dh[idx] = hh;
    dl[idx] = f2bf(wv2 - bf2f(hh));
  } else if (bid < 3584){
    size_t i = ((size_t)(bid-1536)*256 + t) << 3;
    size_t m2 = i >> 7; int k = (int)(i & 127);
    const float* src = zsrc + m2*256 + k;
    float4 a = *(const float4*)src; float4 b2 = *(const float4*)(src+4);
    float vv[8] = {a.x,a.y,a.z,a.w,b2.x,b2.y,b2.z,b2.w};
    short8v oh, ol;
#pragma unroll
    for (int r=0;r<8;r++){
      u16 hh = f2bf(vv[r]);
      oh[r] = (short)hh;
      ol[r] = (short)f2bf(vv[r] - bf2f(hh));
    }
    *(short8v*)(xh + i) = oh;
    *(short8v*)(xl + i) = ol;
  } else {
    int b = bid - 3584, n = t;
    float s = 0.f;
    for (int k2=0;k2<G_;k2++) s = fmaf(cond[b*G_ + k2], fcw[k2*HID_ + n], s);
    condp[b*HID_ + n] = s;
  }
}

__global__ void k_padzero2(u16* __restrict__ XpH, u16* __restrict__ XpL){
  int i = blockIdx.x*256 + threadIdx.x;
  u16* P = (i >> 14) ? XpL : XpH;
  int ii = i & 16383;
  int b = ii >> 10, rr = (ii >> 8) & 3, c = ii & 255;
  int row = (rr < 2) ? rr : (2048 + rr);
  P[((size_t)b*2052 + row)*256 + c] = 0;
}

// EPI: 0 bias, 1 bias+cond, 2 tanh(acc+bias), 3 m+x1 fused flowmix + x0 passthrough (cnd = zsrc)
template<int EPI, int SPLITOUT>
__global__ __launch_bounds__(256,2) void k_mf2(
  const u16* __restrict__ Ah, const u16* __restrict__ Al, int lda, int padA,
  const u16* __restrict__ Bh, const u16* __restrict__ Bl, int ldb,
  const float* __restrict__ bias, const float* __restrict__ cnd,
  void* __restrict__ CH, void* __restrict__ CL, int ldc, int padC, int K)
{
  __shared__ u16 AsmH[4096], AsmL[4096], BsmH[4096], BsmL[4096];
  char* AHB=(char*)AsmH; char* ALB=(char*)AsmL;
  char* BHB=(char*)BsmH; char* BLB=(char*)BsmL;
  const int t = threadIdx.x;
  const int m0 = blockIdx.y << 7, n0 = blockIdx.x << 7;
  const int w = t >> 6, l = t & 63;
  const int wr = (w >> 1) << 6, wc = (w & 1) << 6;
  const int lr = l & 15, lg = l >> 4;
  const int srow = t >> 1, sseg = t & 1;
  const int q = (srow >> 1) & 3;
  const int wo0 = srow*64 + ((((sseg<<1)|0) ^ q) << 4);
  const int wo1 = srow*64 + ((((sseg<<1)|1) ^ q) << 4);
  const int am = m0 + srow;
  const size_t aoff = (size_t)(am + padA*(am >> 11))*lda + (sseg << 4);
  const u16* AhP = Ah + aoff;
  const u16* AlP = Al + aoff;
  const size_t boff = (size_t)(n0 + srow)*ldb + (sseg << 4);
  const u16* BhP = Bh + boff;
  const u16* BlP = Bl + boff;
  const int qa = ((wr + lr) >> 1) & 3, qb = ((wc + lr) >> 1) & 3;
  const int raBase = (wr + lr)*64 + ((lg ^ qa) << 4);
  const int rbBase = (wc + lr)*64 + ((lg ^ qb) << 4);
  f32x4 acc[4][4];
#pragma unroll
  for (int i=0;i<4;i++)
#pragma unroll
    for (int j=0;j<4;j++) acc[i][j] = (f32x4){0.f,0.f,0.f,0.f};

  float4 sah0, sah1, sal0, sal1, sbh0, sbh1, sbl0, sbl1;
  auto LOADF = [&](int kk){
    sah0 = *(const float4*)(AhP + kk); sah1 = *(const float4*)(AhP + kk + 8);
    sal0 = *(const float4*)(AlP + kk); sal1 = *(const float4*)(AlP + kk + 8);
    sbh0 = *(const float4*)(BhP + kk); sbh1 = *(const float4*)(BhP + kk + 8);
    sbl0 = *(const float4*)(BlP + kk); sbl1 = *(const float4*)(BlP + kk + 8);
  };

  LOADF(0);
  for (int k0 = 0; k0 < K; k0 += 32){
    __syncthreads();
    *(float4*)(AHB + wo0) = sah0;  *(float4*)(AHB + wo1) = sah1;
    *(float4*)(ALB + wo0) = sal0;  *(float4*)(ALB + wo1) = sal1;
    *(float4*)(BHB + wo0) = sbh0;  *(float4*)(BHB + wo1) = sbh1;
    *(float4*)(BLB + wo0) = sbl0;  *(float4*)(BLB + wo1) = sbl1;
    if (k0 + 32 < K) LOADF(k0 + 32);
    __syncthreads();
    short8v fah[4], fal[4], fbh[4], fbl[4];
#pragma unroll
    for (int i=0;i<4;i++){
      fah[i] = *(short8v*)(AHB + raBase + i*1024);
      fal[i] = *(short8v*)(ALB + raBase + i*1024);
    }
#pragma unroll
    for (int j=0;j<4;j++){
      fbh[j] = *(short8v*)(BHB + rbBase + j*1024);
      fbl[j] = *(short8v*)(BLB + rbBase + j*1024);
    }
#pragma unroll
    for (int i=0;i<4;i++)
#pragma unroll
      for (int j=0;j<4;j++){
        acc[i][j] = __builtin_amdgcn_mfma_f32_16x16x32_bf16(fah[i], fbh[j], acc[i][j], 0, 0, 0);
        acc[i][j] = __builtin_amdgcn_mfma_f32_16x16x32_bf16(fal[i], fbh[j], acc[i][j], 0, 0, 0);
        acc[i][j] = __builtin_amdgcn_mfma_f32_16x16x32_bf16(fah[i], fbl[j], acc[i][j], 0, 0, 0);
      }
  }

#pragma unroll
  for (int i=0;i<4;i++){
    int mbase = m0 + wr + i*16 + (lg << 2);
#pragma unroll
    for (int j=0;j<4;j++){
      int nn = n0 + wc + j*16 + lr;
      float bs = bias[nn];
      f32x4 v = acc[i][j];
#pragma unroll
      for (int r=0;r<4;r++){
        int m = mbase + r;
        float x = v[r] + bs;
        if (EPI == 1) x += cnd[((m >> 11) << 8) + nn];
        if (EPI == 2) x = tanhf(x);
        if (EPI == 3) x += cnd[(size_t)m*256 + 128 + nn];   // + x1
        size_t ro = (size_t)(m + padC*(m >> 11))*ldc + nn;
        if (SPLITOUT){
          u16 xh = f2bf(x);
          ((u16*)CH)[ro] = xh;
          ((u16*)CL)[ro] = f2bf(x - bf2f(xh));
        } else {
          ((float*)CH)[ro] = x;
          if (EPI == 3)
            ((float*)CH)[(size_t)m*ldc + 128 + nn] = cnd[(size_t)m*256 + nn];
        }
      }
    }
  }
}

// ---------------- MAS: single-wave register-ring scan; loads pinned by memory-asm ----------------
__device__ __forceinline__ void mas_row1(float4 u0, float4 u1, float* Q, int ln, int tr,
                                         unsigned char* __restrict__ cb){
  float v[8] = {u0.x,u0.y,u0.z,u0.w,u1.x,u1.y,u1.z,u1.w};
  float qp = __shfl_up(Q[7], 1);
  if (ln == 0) qp = NEGF;
  unsigned bits = 0; float qs = qp;
#pragma unroll
  for (int i=0;i<8;i++){
    float old = Q[i];
    if (qs > old) bits |= (1u<<i);
    Q[i] = v[i] + fmaxf(old, qs);
    qs = old;
  }
  cb[(size_t)(tr-1)*64 + ln] = (unsigned char)bits;
}

__global__ __launch_bounds__(64,1) void k_mas(const float* __restrict__ lp,
  const int* __restrict__ text, unsigned char* __restrict__ cho, int* __restrict__ path)
{
  const int b = blockIdx.x, ln = threadIdx.x;
  const float* L = lp + (size_t)b*TZ_*TT_;
  const float* Lr = L + ln*8;
  unsigned char* cb = cho + (size_t)b*TZ_*64;
  __shared__ __align__(16) unsigned char lch[3*4096];

  // ===== forward: 8-deep named register ring =====
  float Q[8];
#pragma unroll
  for (int i=0;i<8;i++) Q[i] = NEGF;
  if (ln == 0) Q[0] = L[0];

  float4 P0a = *(const float4*)(Lr + (size_t)1*TT_), P0b = *(const float4*)(Lr + (size_t)1*TT_ + 4);
  float4 P1a = *(const float4*)(Lr + (size_t)2*TT_), P1b = *(const float4*)(Lr + (size_t)2*TT_ + 4);
  float4 P2a = *(const float4*)(Lr + (size_t)3*TT_), P2b = *(const float4*)(Lr + (size_t)3*TT_ + 4);
  float4 P3a = *(const float4*)(Lr + (size_t)4*TT_), P3b = *(const float4*)(Lr + (size_t)4*TT_ + 4);
  float4 P4a = *(const float4*)(Lr + (size_t)5*TT_), P4b = *(const float4*)(Lr + (size_t)5*TT_ + 4);
  float4 P5a = *(const float4*)(Lr + (size_t)6*TT_), P5b = *(const float4*)(Lr + (size_t)6*TT_ + 4);
  float4 P6a = *(const float4*)(Lr + (size_t)7*TT_), P6b = *(const float4*)(Lr + (size_t)7*TT_ + 4);
  float4 P7a = *(const float4*)(Lr + (size_t)8*TT_), P7b = *(const float4*)(Lr + (size_t)8*TT_ + 4);
  asm volatile("" ::: "memory");   // pin prologue loads above this point

  int t0 = 1;
#define MAS_SLOT(Pa, Pb, OFF) \
    mas_row1(Pa, Pb, Q, ln, t0 + OFF, cb); \
    { const float* _s = Lr + (size_t)(t0 + OFF + 8)*TT_; \
      Pa = *(const float4*)_s; Pb = *(const float4*)(_s + 4); } \
    asm volatile("" ::: "memory");
  for (; t0 + 15 <= TZ_ - 1; t0 += 8){
    MAS_SLOT(P0a, P0b, 0)
    MAS_SLOT(P1a, P1b, 1)
    MAS_SLOT(P2a, P2b, 2)
    MAS_SLOT(P3a, P3b, 3)
    MAS_SLOT(P4a, P4b, 4)
    MAS_SLOT(P5a, P5b, 5)
    MAS_SLOT(P6a, P6b, 6)
    MAS_SLOT(P7a, P7b, 7)
  }
#undef MAS_SLOT
  mas_row1(P0a,P0b,Q,ln,t0+0,cb);
  mas_row1(P1a,P1b,Q,ln,t0+1,cb);
  mas_row1(P2a,P2b,Q,ln,t0+2,cb);
  mas_row1(P3a,P3b,Q,ln,t0+3,cb);
  mas_row1(P4a,P4b,Q,ln,t0+4,cb);
  mas_row1(P5a,P5b,Q,ln,t0+5,cb);
  mas_row1(P6a,P6b,Q,ln,t0+6,cb);
  mas_row1(P7a,P7b,Q,ln,t0+7,cb);
  for (int t = t0 + 8; t < TZ_; t++){
    const float* s = Lr + (size_t)t*TT_;
    float4 a = *(const float4*)s;
    float4 c = *(const float4*)(s + 4);
    mas_row1(a, c, Q, ln, t, cb);
  }

  // ===== jlast =====
  int cnt = 0;
#pragma unroll
  for (int i=0;i<8;i++) cnt += (text[b*TT_ + ln*8 + i] != 0) ? 1 : 0;
#pragma unroll
  for (int o2=32;o2;o2>>=1) cnt += __shfl_xor(cnt, o2);
  const int jl = cnt - 1;
  if (ln == 0) path[b*TZ_ + TZ_-1] = jl;

  __syncthreads();   // single wave: drains cb stores (vmcnt) before backtrack reads

  // ===== backtrack: positions p=0..2046 walk rows 2046-p; slot = 64 positions =====
  const int NP = TZ_ - 1;        // 2047
  uint* lchU = (uint*)lch;
  const uint* cbU = (const uint*)cb;
  {
    int r0 = 2046 - ln;
#pragma unroll
    for (int k=0;k<4;k++)
      *(u4v*)&lchU[0*1024 + ln*16 + k*4] = *(const u4v*)&cbU[(size_t)r0*16 + k*4];
    int r1 = 2046 - (64 + ln);
#pragma unroll
    for (int k=0;k<4;k++)
      *(u4v*)&lchU[1*1024 + ln*16 + k*4] = *(const u4v*)&cbU[(size_t)r1*16 + k*4];
  }
  u4v su0, su1, su2, su3;
  {
    int r2 = 2046 - (128 + ln);
    su0 = *(const u4v*)&cbU[(size_t)r2*16 + 0];
    su1 = *(const u4v*)&cbU[(size_t)r2*16 + 4];
    su2 = *(const u4v*)&cbU[(size_t)r2*16 + 8];
    su3 = *(const u4v*)&cbU[(size_t)r2*16 + 12];
  }

  int j = jl;
  unsigned rb0[8], rb1[8]; int rc[8];
  if (ln == 0){
#pragma unroll
    for (int qd=0; qd<8; qd++){
      int cHi = jl >> 3;
      int cLo = (cHi > 0) ? cHi - 1 : 0;
      rb1[qd] = lch[qd*64 + cHi];
      rb0[qd] = lch[qd*64 + cLo];
      rc[qd]  = cHi;
    }
  }
  for (int H = 0; H < 32; H++){
    if (H + 2 < 32){
      uint* wb = lchU + ((H+2)%3)*1024;
      *(u4v*)&wb[ln*16 + 0]  = su0;
      *(u4v*)&wb[ln*16 + 4]  = su1;
      *(u4v*)&wb[ln*16 + 8]  = su2;
      *(u4v*)&wb[ln*16 + 12] = su3;
    }
    if (H + 3 < 32){
      int p = (H+3)*64 + ln;
      if (p <= 2046){
        int r = 2046 - p;
        su0 = *(const u4v*)&cbU[(size_t)r*16 + 0];
        su1 = *(const u4v*)&cbU[(size_t)r*16 + 4];
        su2 = *(const u4v*)&cbU[(size_t)r*16 + 8];
        su3 = *(const u4v*)&cbU[(size_t)r*16 + 12];
      }
    }
    if (ln == 0){
      int pbase = H*64;
#pragma unroll 8
      for (int s = 0; s < 64; s++){
        int p = pbase + s;
        if (p < NP){
          int r = s & 7;
          int jb = j >> 3;
          unsigned byte = (jb == rc[r]) ? rb1[r] : rb0[r];
          j -= (int)((byte >> (j & 7)) & 1u);
          path[b*TZ_ + 2046 - p] = j;
          int pn = p + 8;
          if (pn < NP){
            int hn = (pn >> 6) % 3, sn = pn & 63;
            int cHi = j >> 3;
            int cLo = (cHi > 0) ? cHi - 1 : 0;
            rb1[r] = lch[hn*4096 + sn*64 + cHi];
            rb0[r] = lch[hn*4096 + sn*64 + cLo];
            rc[r]  = cHi;
          }
        }
      }
    }
    __syncthreads();
  }
}

// ---------------- ctx gather + h copy ----------------
__global__ void k_gather(const float* __restrict__ mulv, const int* __restrict__ path,
  const float* __restrict__ h, float* __restrict__ out){
  size_t i = (size_t)blockIdx.x*256 + threadIdx.x;
  const size_t N4 = (size_t)BB*TZ_*(D_/4);
  const size_t H4 = (size_t)BB*TT_*(D_/4);
  if (i < N4){
    size_t row = i >> 6; int c = (int)(i & 63);
    int b = (int)(row >> 11);
    int pj = path[row];
    ((float4*)out)[i] = *(const float4*)(mulv + ((size_t)b*TT_ + pj)*512 + (size_t)c*4);
  } else if (i < N4 + H4){
    size_t k2 = i - N4;
    ((float4*)out)[i] = ((const float4*)h)[k2];
  }
}

extern "C" void kernel_launch(void* const* d_in, const int* in_sizes, int n_in,
                              void* d_out, int out_size, void* d_ws, size_t ws_size,
                              hipStream_t stream)
{
  (void)in_sizes; (void)n_in; (void)out_size; (void)ws_size;
  const float* z      = (const float*)d_in[0];
  const int*   text   = (const int*)  d_in[1];
  const float* cond   = (const float*)d_in[2];
  const float* emb    = (const float*)d_in[3];
  const float* wq     = (const float*)d_in[4];
  const float* wk     = (const float*)d_in[5];
  const float* wv     = (const float*)d_in[6];
  const float* wo     = (const float*)d_in[7];
  const float* bq     = (const float*)d_in[8];
  const float* bk     = (const float*)d_in[9];
  const float* bv     = (const float*)d_in[10];
  const float* bo     = (const float*)d_in[11];
  const float* ln1g   = (const float*)d_in[12];
  const float* ln1b   = (const float*)d_in[13];
  const float* ln2g   = (const float*)d_in[14];
  const float* ln2b   = (const float*)d_in[15];
  const float* w1     = (const float*)d_in[16];
  const float* b1     = (const float*)d_in[17];
  const float* w2     = (const float*)d_in[18];
  const float* b2     = (const float*)d_in[19];
  const float* mu_w   = (const float*)d_in[20];
  const float* mu_b   = (const float*)d_in[21];
  const float* lv_w   = (const float*)d_in[22];
  const float* lv_b   = (const float*)d_in[23];
  const float* f_in   = (const float*)d_in[24];
  const float* f_in_b = (const float*)d_in[25];
  const float* f_cond = (const float*)d_in[26];
  const float* f_conv = (const float*)d_in[27];
  const float* f_convb= (const float*)d_in[28];
  const float* f_out  = (const float*)d_in[29];
  const float* f_outb = (const float*)d_in[30];

  // ---- workspace: 59,363,328 floats = 237,453,312 B (< 237.7MB proven) ----
  float* ws = (float*)d_ws;
  size_t o = 0;
  float* PE   = ws + o; o += (size_t)131072;
  float* H    = ws + o; o += (size_t)2097152;
  float* MULV = ws + o; o += (size_t)4194304;
  float* NC1  = ws + o; o += (size_t)8192;
  float* NC4  = ws + o; o += (size_t)8192;
  float* MR   = ws + o; o += (size_t)32768;
  float* SR   = ws + o; o += (size_t)32768;
  float* CONDP= ws + o; o += (size_t)4096;
  int*   PATH = (int*)(ws + o); o += (size_t)32768;
  u16*  B2H  = (u16*)(ws + o); o += (size_t)2097152;
  u16*  B2L  = (u16*)(ws + o); o += (size_t)2097152;
  float* BIGS = ws + o; o += (size_t)16777216;
  float* BUF1 = ws + o; o += (size_t)4587520;
  float* BUF2 = ws + o; o += (size_t)10485760;
  float* ZCA  = ws + o; o += (size_t)8388608;
  float* ZCB  = ws + o; o += (size_t)8388608;

  float* QKV = BUF2;
  float* Yb  = QKV + 6291456;
  float* VT  = Yb + 2097152;
  float* ATTO= QKV;
  float* QKVT = ZCA;
  float* OT   = QKVT + 1179648;
  float* W1T  = OT + 393216;
  float* W2T  = W1T + 1572864;
  float* MULVT= W2T + 1572864;
  float* BQKV = MULVT + 131072;
  float* MULVB= BQKV + 4608;
  u16*  X0H = (u16*)BUF1;
  u16*  X0L = X0H + 4194304;
  u16*  WITH = X0L + 4194304;
  u16*  WITL = WITH + 32768;
  u16*  WCTH = WITL + 32768;
  u16*  WCTL = WCTH + 327680;
  u16*  WOTH = WCTL + 327680;
  u16*  WOTL = WOTH + 32768;
  u16*  XpH = (u16*)BIGS;
  u16*  XpL = XpH + 8404992;
  u16*  H2H = (u16*)BUF2;
  u16*  H2L = H2H + 8388608;
  unsigned char* CHO = (unsigned char*)ZCA;

  k_pe   <<<dim3(TT_),    dim3(D_), 0, stream>>>(PE);
  k_embed<<<dim3(BB*TT_), dim3(D_), 0, stream>>>(text, emb, PE, H);
  k_wt   <<<dim3(16,74), 256, 0, stream>>>(wq,wk,wv,wo,mu_w,lv_w,w1,w2, QKVT,OT,MULVT,W1T,W2T);
  k_bcat <<<dim3(20), 256, 0, stream>>>(bq,bk,bv,mu_b,lv_b, BQKV, MULVB);

  for (int l=0;l<L_;l++){
    k_mg<4,0,0,0><<<dim3(6,64,1),256,0,stream>>>(
      H, nullptr, 256, 0,0,  QKVT + (size_t)l*196608, nullptr, 256, 0,0,
      BQKV + l*768, nullptr, nullptr, nullptr, QKV, 768, 0,0, 256);
    k_vt <<<dim3(4,8,16),256,0,stream>>>(QKV, VT);
    k_mg<4,2,0,0><<<dim3(4,4,64),256,0,stream>>>(
      QKV, nullptr, 768, 393216, 64,  QKV+256, nullptr, 768, 393216, 64,
      nullptr, text, nullptr, nullptr, BIGS, 512, 1048576, 262144, 64);
    k_rowstat<<<dim3(BB*HEADS_*TT_/4),256,0,stream>>>(BIGS, MR, SR);
    k_mg<2,0,4,0><<<dim3(1,4,64),256,0,stream>>>(
      BIGS, nullptr, 512, 1048576, 262144,  VT, nullptr, 512, 131072, 32768,
      nullptr, nullptr, MR, SR, Yb, 256, 131072, 64, 512);
    k_mg<4,0,0,0><<<dim3(2,64,1),256,0,stream>>>(
      Yb, nullptr, 256, 0,0,  OT + (size_t)l*65536, nullptr, 256, 0,0,
      bo + l*256, nullptr, nullptr, nullptr, ATTO, 256, 0,0, 256);
    k_lnres<<<dim3(BB*TT_),256,0,stream>>>(ATTO, ln1g+l*D_, ln1b+l*D_, H);
    k_mg<4,1,0,0><<<dim3(8,64,1),256,0,stream>>>(
      H, nullptr, 256, 0,0,  W1T + (size_t)l*262144, nullptr, 256, 0,0,
      b1 + l*1024, nullptr, nullptr, nullptr, BIGS, 1024, 0,0, 256);
    k_mg<4,0,0,0><<<dim3(2,64,1),256,0,stream>>>(
      BIGS, nullptr, 1024, 0,0,  W2T + (size_t)l*262144, nullptr, 1024, 0,0,
      b2 + l*256, nullptr, nullptr, nullptr, ATTO, 256, 0,0, 1024);
    k_lnres<<<dim3(BB*TT_),256,0,stream>>>(ATTO, ln2g+l*D_, ln2b+l*D_, H);
  }

  k_mg<4,0,0,0><<<dim3(4,64,1),256,0,stream>>>(
    H, nullptr, 256, 0,0,  MULVT, nullptr, 256, 0,0,
    MULVB, nullptr, nullptr, nullptr, MULV, 512, 0,0, 256);
  k_prep<<<dim3(BB*TT_),256,0,stream>>>(MULV, B2H, B2L, NC1, NC4);

  // ---- flows ----
  k_padzero2<<<dim3(128),256,0,stream>>>(XpH, XpL);
  const float* zsrc = z;
  for (int f=0; f<FLOWS_; f++){
    k_fprep<<<dim3(3600),256,0,stream>>>(
        f_in + (size_t)f*(CH_/2)*HID_, f_conv + (size_t)f*KCV*HID_*HID_,
        f_out + (size_t)f*HID_*(CH_/2),
        WITH, WITL, WCTH, WCTL, WOTH, WOTL,
        zsrc, X0H, X0L,
        cond, f_cond + (size_t)f*G_*HID_, CONDP);
    k_mf2<1,1><<<dim3(2,256),256,0,stream>>>(X0H, X0L, 128, 0, WITH, WITL, 128,
        f_in_b + f*HID_, CONDP, (void*)(XpH + 512), (void*)(XpL + 512), 256, 4, 128);
    k_mf2<2,1><<<dim3(2,256),256,0,stream>>>(XpH, XpL, 256, 4, WCTH, WCTL, 1280,
        f_convb + f*HID_, nullptr, (void*)H2H, (void*)H2L, 256, 0, 1280);
    float* zdst = (f & 1) ? ZCB : ZCA;
    k_mf2<3,0><<<dim3(1,256),256,0,stream>>>(H2H, H2L, 256, 0, WOTH, WOTL, 256,
        f_outb + f*(CH_/2), zsrc, (void*)zdst, nullptr, 256, 0, 256);
    zsrc = zdst;
  }

  // logp
  k_mg<4,3,2,1><<<dim3(4,16,16),256,0,stream>>>(
    zsrc, nullptr, 256, 2097152, 524288,
    B2H, B2L, 512, 1048576, 262144,
    nullptr, text, NC1, NC4, BIGS, 512, 4194304, 1048576, 512);

  k_mas<<<dim3(BB),64,0,stream>>>(BIGS, text, CHO, PATH);
  k_gather<<<dim3((BB*TZ_*D_/4 + BB*TT_*D_/4)/256),256,0,stream>>>(MULV, PATH, H, (float*)d_out);
}